// Round 11
// baseline (112.825 us; speedup 1.0000x reference)
//
#include <hip/hip_runtime.h>
#include <hip/hip_bf16.h>
#include <math.h>

constexpr int B = 4;
constexpr int N = 1024;
constexpr float NEGINF = -9000000000000000.0f;

// ---------- prep: 256 blocks (b x 16-row tile) x 256 thr. (unchanged) ----------
__global__ __launch_bounds__(256) void gat_prep(
    const float* __restrict__ h, const float* __restrict__ lin_w,
    const float* __restrict__ lin_b, const float* __restrict__ W_w,
    const float* __restrict__ a_g,
    float* __restrict__ hp, float* __restrict__ u_out, float* __restrict__ vT,
    float* __restrict__ au_out, float* __restrict__ av_out) {
  __shared__ float hs[64 * 18];
  __shared__ float wl[64 * 68];
  __shared__ float w1[64 * 68];
  __shared__ float w2[64 * 68];
  __shared__ float hpT[64 * 18];
  __shared__ float vt_s[64 * 17];
  __shared__ float ared[2][16 * 17];
  __shared__ float lb_s[64], a_s[64];

  const int b = blockIdx.x >> 6;
  const int n0 = (blockIdx.x & 63) << 4;
  const int tid = threadIdx.x;

  if (tid < 64) { lb_s[tid] = lin_b[tid]; a_s[tid] = a_g[tid]; }
  for (int idx = tid; idx < 1024; idx += 256) {
    const int r = idx >> 6, c = idx & 63;
    hs[c * 18 + r] = h[((b << 10) + n0 + r) * 64 + c];
  }
  for (int idx = tid; idx < 4096; idx += 256) {
    const int o = idx >> 6, f = idx & 63;
    wl[f * 68 + o] = lin_w[idx];
    w1[f * 68 + o] = W_w[o * 128 + f];
    w2[f * 68 + o] = W_w[o * 128 + 64 + f];
  }
  __syncthreads();

  const int tf = tid & 15, tn = tid >> 4;
  float ahp[4];
#pragma unroll
  for (int r = 0; r < 4; ++r) ahp[r] = lb_s[tf * 4 + r];
#pragma unroll 8
  for (int k = 0; k < 64; ++k) {
    const float hv = hs[k * 18 + tn];
    const float4 l4 = *(const float4*)&wl[k * 68 + tf * 4];
    ahp[0] = fmaf(hv, l4.x, ahp[0]);
    ahp[1] = fmaf(hv, l4.y, ahp[1]);
    ahp[2] = fmaf(hv, l4.z, ahp[2]);
    ahp[3] = fmaf(hv, l4.w, ahp[3]);
  }
  const int row = (b << 10) + n0 + tn;
  *(float4*)&hp[row * 64 + tf * 4] = make_float4(ahp[0], ahp[1], ahp[2], ahp[3]);
#pragma unroll
  for (int r = 0; r < 4; ++r) hpT[(tf * 4 + r) * 18 + tn] = ahp[r];
  __syncthreads();

  float aU[4] = {0.f, 0.f, 0.f, 0.f}, aV[4] = {0.f, 0.f, 0.f, 0.f};
#pragma unroll 8
  for (int k = 0; k < 64; ++k) {
    const float hv = hpT[k * 18 + tn];
    const float4 u4 = *(const float4*)&w1[k * 68 + tf * 4];
    const float4 v4 = *(const float4*)&w2[k * 68 + tf * 4];
    aU[0] = fmaf(hv, u4.x, aU[0]);
    aU[1] = fmaf(hv, u4.y, aU[1]);
    aU[2] = fmaf(hv, u4.z, aU[2]);
    aU[3] = fmaf(hv, u4.w, aU[3]);
    aV[0] = fmaf(hv, v4.x, aV[0]);
    aV[1] = fmaf(hv, v4.y, aV[1]);
    aV[2] = fmaf(hv, v4.z, aV[2]);
    aV[3] = fmaf(hv, v4.w, aV[3]);
  }
  *(float4*)&u_out[row * 64 + tf * 4] = make_float4(aU[0], aU[1], aU[2], aU[3]);
  float aup = 0.f, avp = 0.f;
#pragma unroll
  for (int r = 0; r < 4; ++r) {
    vt_s[(tf * 4 + r) * 17 + tn] = aV[r];
    aup = fmaf(a_s[tf * 4 + r], aU[r], aup);
    avp = fmaf(a_s[tf * 4 + r], aV[r], avp);
  }
  ared[0][tn * 17 + tf] = aup;
  ared[1][tn * 17 + tf] = avp;
  __syncthreads();
  for (int idx = tid; idx < 1024; idx += 256) {
    const int f = idx >> 4, n = idx & 15;
    vT[(((b << 6) + f) << 10) + n0 + n] = vt_s[f * 17 + n];
  }
  if (tid < 32) {
    const int which = tid >> 4, rr = tid & 15;
    float s2 = 0.f;
#pragma unroll
    for (int t = 0; t < 16; ++t) s2 += ared[which][rr * 17 + t];
    if (which == 0) au_out[(b << 10) + n0 + rr] = s2;
    else av_out[(b << 10) + n0 + rr] = s2;
  }
}

// ---------- attn: 512 blocks (b x 8-row tile) x 512 threads (8 waves).
// Phase 1/2: thread owns j = 2*tid, 2*tid+1.  Phase 3: (f-quad, j-subgroup).
__global__ __launch_bounds__(512) void gat_attn(
    const float* __restrict__ u_g, const float* __restrict__ vT,
    const float* __restrict__ hp, const int* __restrict__ adj,
    const float* __restrict__ a_g, const float* __restrict__ au_g,
    const float* __restrict__ av_g, float* __restrict__ out) {
  __shared__ float p_s[8 * 1024];   // [j][8i] granules: 32 KB
  __shared__ float wp_s[8 * 512];   // wave partials [w][i][f]: 16 KB
  __shared__ float u_s[64 * 8];     // [f][i]
  __shared__ float a_s[64];
  __shared__ float au_s[8];
  __shared__ float wred[8][8];      // [wave][i]
  __shared__ float wsum[8][8];
  __shared__ float rinv_s[8];

  const int b = blockIdx.x >> 7;
  const int i0 = (blockIdx.x & 127) << 3;
  const int tid = threadIdx.x;
  const int lane = tid & 63, w = tid >> 6;
  const int j0 = tid << 1;  // 2 j's per thread

  if (tid < 64) a_s[tid] = a_g[tid];
  if (tid < 8) au_s[tid] = au_g[(b << 10) + i0 + tid];
  {
    const int i = tid >> 6, f = tid & 63;
    u_s[f * 8 + i] = u_g[((b << 10) + i0 + i) * 64 + f];
  }
  __syncthreads();

  // ---- Phase 1: d[i][k] = sum_f a_f * |u_if + v_(j0+k)f| ----
  float e[8][2];
#pragma unroll
  for (int i = 0; i < 8; ++i) { e[i][0] = 0.f; e[i][1] = 0.f; }

  const float* vb = vT + ((b << 6) << 10) + j0;
#pragma unroll 4
  for (int f = 0; f < 64; ++f) {
    const float af = a_s[f];
    const float2 v2 = *(const float2*)&vb[f << 10];
    const float4 ua = *(const float4*)&u_s[f * 8];
    const float4 ub = *(const float4*)&u_s[f * 8 + 4];
    const float uu[8] = {ua.x, ua.y, ua.z, ua.w, ub.x, ub.y, ub.z, ub.w};
    const float vv[2] = {v2.x, v2.y};
#pragma unroll
    for (int i = 0; i < 8; ++i) {
      e[i][0] = fmaf(af, fabsf(uu[i] + vv[0]), e[i][0]);
      e[i][1] = fmaf(af, fabsf(uu[i] + vv[1]), e[i][1]);
    }
  }
  // e = 0.6(au+av) + 0.4 d, then adjacency mask (int2 per row)
  const float2 av2 = *(const float2*)&av_g[(b << 10) + j0];
  const float avv[2] = {0.6f * av2.x, 0.6f * av2.y};
  float au6[8];
#pragma unroll
  for (int i = 0; i < 8; ++i) au6[i] = 0.6f * au_s[i];
  const int* adjb = adj + (((b << 10) + i0) << 10) + j0;
#pragma unroll
  for (int i = 0; i < 8; ++i) {
    const int2 ad = *(const int2*)&adjb[i << 10];
    const float e0 = fmaf(0.4f, e[i][0], au6[i] + avv[0]);
    const float e1 = fmaf(0.4f, e[i][1], au6[i] + avv[1]);
    e[i][0] = ad.x > 0 ? e0 : NEGINF;
    e[i][1] = ad.y > 0 ? e1 : NEGINF;
  }

  // ---- Phase 2: softmax in registers ----
#pragma unroll
  for (int i = 0; i < 8; ++i) {
    float mm = fmaxf(e[i][0], e[i][1]);
#pragma unroll
    for (int off = 32; off; off >>= 1) mm = fmaxf(mm, __shfl_xor(mm, off));
    if (lane == 0) wred[w][i] = mm;
  }
  __syncthreads();
#pragma unroll
  for (int i = 0; i < 8; ++i) {
    float mi = wred[0][i];
#pragma unroll
    for (int ww = 1; ww < 8; ++ww) mi = fmaxf(mi, wred[ww][i]);
    e[i][0] = __expf(e[i][0] - mi);
    e[i][1] = __expf(e[i][1] - mi);
    float ss = e[i][0] + e[i][1];
#pragma unroll
    for (int off = 32; off; off >>= 1) ss += __shfl_xor(ss, off);
    if (lane == 0) wsum[w][i] = ss;
  }
  __syncthreads();
  if (tid < 8) {
    float st = 0.f;
#pragma unroll
    for (int ww = 0; ww < 8; ++ww) st += wsum[ww][tid];
    rinv_s[tid] = 1.0f / st;
  }
  // p granules: [j][8i], 32 B each. Store: lane stride 64 B -> 2-way (free).
#pragma unroll
  for (int k = 0; k < 2; ++k) {
    const int j = j0 + k;
    *(float4*)&p_s[j << 3] = make_float4(e[0][k], e[1][k], e[2][k], e[3][k]);
    *(float4*)&p_s[(j << 3) + 4] = make_float4(e[4][k], e[5][k], e[6][k], e[7][k]);
  }
  __syncthreads();

  // ---- Phase 3: h' = p @ hp ; thread = (f-quad fq, j-subgroup g of 32) ----
  // j = 32*jj + g -> within a wave the 4 g's are consecutive j: p granule
  // reads hit banks 0/8/16/24 (conflict-free), hp loads stay coalesced.
  const int fq = tid & 15, g = tid >> 4;
  float4 acc[8];
#pragma unroll
  for (int i = 0; i < 8; ++i) acc[i] = make_float4(0.f, 0.f, 0.f, 0.f);
  const float* hpb = hp + (b << 16) + (fq << 2);
#pragma unroll 4
  for (int jj = 0; jj < 32; ++jj) {
    const int j = (jj << 5) + g;
    const float4 h4 = *(const float4*)&hpb[j << 6];
    const float4 pA = *(const float4*)&p_s[j << 3];
    const float4 pB = *(const float4*)&p_s[(j << 3) + 4];
    acc[0].x = fmaf(pA.x, h4.x, acc[0].x);
    acc[0].y = fmaf(pA.x, h4.y, acc[0].y);
    acc[0].z = fmaf(pA.x, h4.z, acc[0].z);
    acc[0].w = fmaf(pA.x, h4.w, acc[0].w);
    acc[1].x = fmaf(pA.y, h4.x, acc[1].x);
    acc[1].y = fmaf(pA.y, h4.y, acc[1].y);
    acc[1].z = fmaf(pA.y, h4.z, acc[1].z);
    acc[1].w = fmaf(pA.y, h4.w, acc[1].w);
    acc[2].x = fmaf(pA.z, h4.x, acc[2].x);
    acc[2].y = fmaf(pA.z, h4.y, acc[2].y);
    acc[2].z = fmaf(pA.z, h4.z, acc[2].z);
    acc[2].w = fmaf(pA.z, h4.w, acc[2].w);
    acc[3].x = fmaf(pA.w, h4.x, acc[3].x);
    acc[3].y = fmaf(pA.w, h4.y, acc[3].y);
    acc[3].z = fmaf(pA.w, h4.z, acc[3].z);
    acc[3].w = fmaf(pA.w, h4.w, acc[3].w);
    acc[4].x = fmaf(pB.x, h4.x, acc[4].x);
    acc[4].y = fmaf(pB.x, h4.y, acc[4].y);
    acc[4].z = fmaf(pB.x, h4.z, acc[4].z);
    acc[4].w = fmaf(pB.x, h4.w, acc[4].w);
    acc[5].x = fmaf(pB.y, h4.x, acc[5].x);
    acc[5].y = fmaf(pB.y, h4.y, acc[5].y);
    acc[5].z = fmaf(pB.y, h4.z, acc[5].z);
    acc[5].w = fmaf(pB.y, h4.w, acc[5].w);
    acc[6].x = fmaf(pB.z, h4.x, acc[6].x);
    acc[6].y = fmaf(pB.z, h4.y, acc[6].y);
    acc[6].z = fmaf(pB.z, h4.z, acc[6].z);
    acc[6].w = fmaf(pB.z, h4.w, acc[6].w);
    acc[7].x = fmaf(pB.w, h4.x, acc[7].x);
    acc[7].y = fmaf(pB.w, h4.y, acc[7].y);
    acc[7].z = fmaf(pB.w, h4.z, acc[7].z);
    acc[7].w = fmaf(pB.w, h4.w, acc[7].w);
  }
  // reduce across the 4 j-subgroups of this wave (lane bits 4,5)
#pragma unroll
  for (int i = 0; i < 8; ++i) {
#pragma unroll
    for (int off = 16; off <= 32; off <<= 1) {
      acc[i].x += __shfl_xor(acc[i].x, off);
      acc[i].y += __shfl_xor(acc[i].y, off);
      acc[i].z += __shfl_xor(acc[i].z, off);
      acc[i].w += __shfl_xor(acc[i].w, off);
    }
  }
  if (lane < 16) {
#pragma unroll
    for (int i = 0; i < 8; ++i)
      *(float4*)&wp_s[((w << 3) + i) << 6 | (fq << 2)] = acc[i];
  }
  __syncthreads();
  {
    const int i = tid >> 6, f = tid & 63;
    float r = 0.f;
#pragma unroll
    for (int ww = 0; ww < 8; ++ww) r += wp_s[((ww << 3) + i) << 6 | f];
    r *= rinv_s[i];
    out[((b << 10) + i0 + i) * 64 + f] = r > 0.f ? r : expm1f(r);
  }
}

extern "C" void kernel_launch(void* const* d_in, const int* in_sizes, int n_in,
                              void* d_out, int out_size, void* d_ws, size_t ws_size,
                              hipStream_t stream) {
  const float* h = (const float*)d_in[0];
  const int* adj = (const int*)d_in[1];
  const float* lin_w = (const float*)d_in[2];
  const float* lin_b = (const float*)d_in[3];
  const float* W_w = (const float*)d_in[4];
  const float* a = (const float*)d_in[5];
  float* outp = (float*)d_out;

  float* ws = (float*)d_ws;
  float* hp = ws;                 // 262144
  float* u = ws + 262144;         // 262144
  float* vT = ws + 524288;        // 262144
  float* au = ws + 786432;        // 4096
  float* av = ws + 790528;        // 4096

  gat_prep<<<dim3(256), dim3(256), 0, stream>>>(h, lin_w, lin_b, W_w, a,
                                                hp, u, vT, au, av);
  gat_attn<<<dim3(512), dim3(512), 0, stream>>>(u, vT, hp, adj, a, au, av, outp);
}

// Round 13
// 110.300 us; speedup vs baseline: 1.0229x; 1.0229x over previous
//
#include <hip/hip_runtime.h>
#include <hip/hip_bf16.h>
#include <math.h>

constexpr int B = 4;
constexpr int N = 1024;
constexpr float NEGINF = -9000000000000000.0f;

// ---------- prep: 512 blocks (b x 8-row tile) x 512 thr (wave per row).
// hp = h@lin_w^T+lin_b ; u = hp@W1^T ; v = hp@W2^T ; au = u.a ; av = v.a ; vT.
// All row data via wave-uniform LDS broadcasts; weights in stride-65 tiles.
__global__ __launch_bounds__(512) void gat_prep(
    const float* __restrict__ h, const float* __restrict__ lin_w,
    const float* __restrict__ lin_b, const float* __restrict__ W_w,
    const float* __restrict__ a_g,
    float* __restrict__ hp_g, float* __restrict__ u_out, float* __restrict__ vT_g,
    float* __restrict__ au_out, float* __restrict__ av_out) {
  __shared__ float wlT[64 * 65];  // [k][o] = lin_w[o][k]
  __shared__ float w1T[64 * 65];  // [k][o] = W_w[o][k]
  __shared__ float w2T[64 * 65];  // [k][o] = W_w[o][64+k]
  __shared__ float hs[512];       // [n][k] own 8 rows
  __shared__ float hp_s[512];     // [n][k]
  __shared__ float v_s[64 * 9];   // [f][n] stride 9
  __shared__ float a_s[64];

  const int b = blockIdx.x >> 7;
  const int n0 = (blockIdx.x & 127) << 3;
  const int tid = threadIdx.x;
  const int lane = tid & 63, w = tid >> 6;
  const int tn = w, tf = lane;    // wave per row, lane per col

  if (tid < 64) a_s[tid] = a_g[tid];
  for (int idx = tid; idx < 4096; idx += 512) {
    const int o = idx >> 6, k = idx & 63;
    wlT[k * 65 + o] = lin_w[idx];
    w1T[k * 65 + o] = W_w[o * 128 + k];
    w2T[k * 65 + o] = W_w[o * 128 + 64 + k];
  }
  hs[tid] = h[(((b << 10) + n0) << 6) + tid];
  __syncthreads();

  // hp[tn][tf]
  float hpv = lin_b[tf];
#pragma unroll 8
  for (int k = 0; k < 64; ++k)
    hpv = fmaf(hs[tn * 64 + k], wlT[k * 65 + tf], hpv);  // hs wave-uniform
  const int row = (b << 10) + n0 + tn;
  hp_g[(row << 6) + tf] = hpv;
  hp_s[tn * 64 + tf] = hpv;
  __syncthreads();

  // u, v
  float uu = 0.f, vv = 0.f;
#pragma unroll 8
  for (int k = 0; k < 64; ++k) {
    const float hh = hp_s[tn * 64 + k];  // wave-uniform
    uu = fmaf(hh, w1T[k * 65 + tf], uu);
    vv = fmaf(hh, w2T[k * 65 + tf], vv);
  }
  u_out[(row << 6) + tf] = uu;
  v_s[tf * 9 + tn] = vv;
  float aup = a_s[tf] * uu, avp = a_s[tf] * vv;
#pragma unroll
  for (int off = 32; off; off >>= 1) {
    aup += __shfl_xor(aup, off);
    avp += __shfl_xor(avp, off);
  }
  if (tf == 0) {
    au_out[row] = aup;
    av_out[row] = avp;
  }
  __syncthreads();
  {  // vT: [f][n0..n0+7]
    const int f = tid >> 3, n = tid & 7;
    vT_g[(((b << 6) + f) << 10) + n0 + n] = v_s[f * 9 + n];
  }
}

// ---------- attn: round-10 form, byte-identical (best measured). ----------
// 1024 blocks (b x 4-row tile) x 256 threads.
__global__ __launch_bounds__(256) void gat_attn(
    const float* __restrict__ u_g, const float* __restrict__ vT,
    const float* __restrict__ hp, const int* __restrict__ adj,
    const float* __restrict__ a_g, const float* __restrict__ au_g,
    const float* __restrict__ av_g, float* __restrict__ out) {
  __shared__ float p_s[4 * 1024];  // 16 KB: p granules, then reduction buffer
  __shared__ float u_s[64 * 4];    // [f][i]
  __shared__ float a_s[64];
  __shared__ float au_s[4];
  __shared__ float wred[4][4];     // [wave][i]
  __shared__ float wsum[4][4];
  __shared__ float rinv_s[4];

  const int b = blockIdx.x >> 8;
  const int i0 = (blockIdx.x & 255) << 2;
  const int tid = threadIdx.x;
  const int lane = tid & 63, w = tid >> 6;
  const int j0 = tid << 2;

  if (tid < 64) a_s[tid] = a_g[tid];
  if (tid < 4) au_s[tid] = au_g[(b << 10) + i0 + tid];
  {
    const int i = tid >> 6, f = tid & 63;
    u_s[f * 4 + i] = u_g[((b << 10) + i0 + i) * 64 + f];
  }
  __syncthreads();

  // ---- Phase 1: d[i][k] = sum_f a_f * |u_if + v_(j0+k)f| ----
  float e[4][4];
#pragma unroll
  for (int i = 0; i < 4; ++i)
#pragma unroll
    for (int k = 0; k < 4; ++k) e[i][k] = 0.f;

  const float* vb = vT + ((b << 6) << 10) + j0;
#pragma unroll 4
  for (int f = 0; f < 64; ++f) {
    const float af = a_s[f];
    const float4 v4 = *(const float4*)&vb[f << 10];
    const float4 u4 = *(const float4*)&u_s[f * 4];
    const float uu[4] = {u4.x, u4.y, u4.z, u4.w};
    const float vv[4] = {v4.x, v4.y, v4.z, v4.w};
#pragma unroll
    for (int i = 0; i < 4; ++i)
#pragma unroll
      for (int k = 0; k < 4; ++k)
        e[i][k] = fmaf(af, fabsf(uu[i] + vv[k]), e[i][k]);
  }
  // e = 0.6(au+av) + 0.4 d, then adjacency mask (int4 per row)
  const float4 av4 = *(const float4*)&av_g[(b << 10) + j0];
  const float avv[4] = {0.6f * av4.x, 0.6f * av4.y, 0.6f * av4.z, 0.6f * av4.w};
  float au6[4];
#pragma unroll
  for (int i = 0; i < 4; ++i) au6[i] = 0.6f * au_s[i];
  const int* adjb = adj + (((b << 10) + i0) << 10) + j0;
#pragma unroll
  for (int i = 0; i < 4; ++i) {
    const int4 ad = *(const int4*)&adjb[i << 10];
    const int adv[4] = {ad.x, ad.y, ad.z, ad.w};
#pragma unroll
    for (int k = 0; k < 4; ++k) {
      const float ev = fmaf(0.4f, e[i][k], au6[i] + avv[k]);
      e[i][k] = adv[k] > 0 ? ev : NEGINF;
    }
  }

  // ---- Phase 2: softmax in registers ----
#pragma unroll
  for (int i = 0; i < 4; ++i) {
    float mm = fmaxf(fmaxf(e[i][0], e[i][1]), fmaxf(e[i][2], e[i][3]));
#pragma unroll
    for (int off = 32; off; off >>= 1) mm = fmaxf(mm, __shfl_xor(mm, off));
    if (lane == 0) wred[w][i] = mm;
  }
  __syncthreads();
#pragma unroll
  for (int i = 0; i < 4; ++i) {
    const float mi = fmaxf(fmaxf(wred[0][i], wred[1][i]),
                           fmaxf(wred[2][i], wred[3][i]));
#pragma unroll
    for (int k = 0; k < 4; ++k) e[i][k] = __expf(e[i][k] - mi);
    float ss = e[i][0] + e[i][1] + e[i][2] + e[i][3];
#pragma unroll
    for (int off = 32; off; off >>= 1) ss += __shfl_xor(ss, off);
    if (lane == 0) wsum[w][i] = ss;
  }
  __syncthreads();
  if (tid < 4)
    rinv_s[tid] = 1.0f / (wsum[0][tid] + wsum[1][tid] + wsum[2][tid] + wsum[3][tid]);

  // p granules: j's 4 i-values at float index 4*(j>>2) + (j&3)*1024.
#pragma unroll
  for (int k = 0; k < 4; ++k)
    *(float4*)&p_s[(tid << 2) + (k << 10)] =
        make_float4(e[0][k], e[1][k], e[2][k], e[3][k]);
  __syncthreads();

  // ---- Phase 3: h' = p @ hp ; thread = (f-quad fq, j-group g of 64) ----
  const int fq = tid & 15, g = tid >> 4;
  float4 acc[4];
#pragma unroll
  for (int i = 0; i < 4; ++i) acc[i] = make_float4(0.f, 0.f, 0.f, 0.f);
  const float* hpb = hp + (b << 16) + (fq << 2);
#pragma unroll 4
  for (int jj = 0; jj < 64; ++jj) {
    const int j = (g << 6) + jj;
    const float4 h4 = *(const float4*)&hpb[j << 6];
    const float4 p4 = *(const float4*)&p_s[(j & ~3) + ((j & 3) << 10)];
    acc[0].x = fmaf(p4.x, h4.x, acc[0].x);
    acc[0].y = fmaf(p4.x, h4.y, acc[0].y);
    acc[0].z = fmaf(p4.x, h4.z, acc[0].z);
    acc[0].w = fmaf(p4.x, h4.w, acc[0].w);
    acc[1].x = fmaf(p4.y, h4.x, acc[1].x);
    acc[1].y = fmaf(p4.y, h4.y, acc[1].y);
    acc[1].z = fmaf(p4.y, h4.z, acc[1].z);
    acc[1].w = fmaf(p4.y, h4.w, acc[1].w);
    acc[2].x = fmaf(p4.z, h4.x, acc[2].x);
    acc[2].y = fmaf(p4.z, h4.y, acc[2].y);
    acc[2].z = fmaf(p4.z, h4.z, acc[2].z);
    acc[2].w = fmaf(p4.z, h4.w, acc[2].w);
    acc[3].x = fmaf(p4.w, h4.x, acc[3].x);
    acc[3].y = fmaf(p4.w, h4.y, acc[3].y);
    acc[3].z = fmaf(p4.w, h4.z, acc[3].z);
    acc[3].w = fmaf(p4.w, h4.w, acc[3].w);
  }
  __syncthreads();  // p_s reads done; reuse as red[g][i][f]
#pragma unroll
  for (int i = 0; i < 4; ++i)
    *(float4*)&p_s[(g << 8) + (i << 6) + (fq << 2)] = acc[i];
  __syncthreads();
  {
    const int i = tid >> 6, f = tid & 63;
    float r = 0.f;
#pragma unroll
    for (int gg = 0; gg < 16; ++gg) r += p_s[(gg << 8) + (i << 6) + f];
    r *= rinv_s[i];
    out[((b << 10) + i0 + i) * 64 + f] = r > 0.f ? r : expm1f(r);
  }
}

extern "C" void kernel_launch(void* const* d_in, const int* in_sizes, int n_in,
                              void* d_out, int out_size, void* d_ws, size_t ws_size,
                              hipStream_t stream) {
  const float* h = (const float*)d_in[0];
  const int* adj = (const int*)d_in[1];
  const float* lin_w = (const float*)d_in[2];
  const float* lin_b = (const float*)d_in[3];
  const float* W_w = (const float*)d_in[4];
  const float* a = (const float*)d_in[5];
  float* outp = (float*)d_out;

  float* ws = (float*)d_ws;
  float* hp = ws;                 // 262144
  float* u = ws + 262144;         // 262144
  float* vT = ws + 524288;        // 262144
  float* au = ws + 786432;        // 4096
  float* av = ws + 790528;        // 4096

  gat_prep<<<dim3(512), dim3(512), 0, stream>>>(h, lin_w, lin_b, W_w, a,
                                                hp, u, vT, au, av);
  gat_attn<<<dim3(1024), dim3(256), 0, stream>>>(u, vT, hp, adj, a, au, av, outp);
}